// Round 13
// baseline (69.542 us; speedup 1.0000x reference)
//
#include <hip/hip_runtime.h>
#include <hip/hip_bf16.h>
#include <hip/hip_cooperative_groups.h>
#include <math.h>

namespace cg = cooperative_groups;

#define NBINS   1024
#define NPART   512     // grid: 512 blocks x 128 threads = 2 blocks/CU (co-resident)
#define LSTRIDE 72      // ushorts per bin-row: 144B, 16B-aligned slots

typedef __attribute__((ext_vector_type(8)))  short short8;   // 8 bf16 = 4 VGPR
typedef __attribute__((ext_vector_type(16))) float f32x16;   // MFMA 32x32 acc

// Single cooperative kernel: hist phase (R12-verified body) -> grid.sync() ->
// reduce+finalize phase (R12's bins-complete reduce, re-geometried to 128 thr).
// ws: gC[NPART*NBINS] partials (2MB). out zeroed in phase 1, ordered by sync.

__device__ __forceinline__ void make_trees(const float v[10], float valid,
                                           float hi[32], float lo[32])
{
    {
        float t2[2], t4[4], t8[8], t16[16];
        t2[0] = valid * (1.0f - v[0]); t2[1] = valid * v[0];
        #pragma unroll
        for (int k = 0; k < 4; ++k)  t4[k]  = t2[k >> 1]  * ((k & 1) ? v[1] : 1.0f - v[1]);
        #pragma unroll
        for (int k = 0; k < 8; ++k)  t8[k]  = t4[k >> 1]  * ((k & 1) ? v[2] : 1.0f - v[2]);
        #pragma unroll
        for (int k = 0; k < 16; ++k) t16[k] = t8[k >> 1]  * ((k & 1) ? v[3] : 1.0f - v[3]);
        #pragma unroll
        for (int k = 0; k < 32; ++k) hi[k]  = t16[k >> 1] * ((k & 1) ? v[4] : 1.0f - v[4]);
    }
    {
        float t2[2], t4[4], t8[8], t16[16];
        t2[0] = 1.0f - v[5]; t2[1] = v[5];
        #pragma unroll
        for (int k = 0; k < 4; ++k)  t4[k]  = t2[k >> 1]  * ((k & 1) ? v[6] : 1.0f - v[6]);
        #pragma unroll
        for (int k = 0; k < 8; ++k)  t8[k]  = t4[k >> 1]  * ((k & 1) ? v[7] : 1.0f - v[7]);
        #pragma unroll
        for (int k = 0; k < 16; ++k) t16[k] = t8[k >> 1]  * ((k & 1) ? v[8] : 1.0f - v[8]);
        #pragma unroll
        for (int k = 0; k < 32; ++k) lo[k]  = t16[k >> 1] * ((k & 1) ? v[9] : 1.0f - v[9]);
    }
}

__global__ __launch_bounds__(128, 2) void fused_kernel(const float* __restrict__ act,
                                                       float* __restrict__ gC,
                                                       float* __restrict__ out,
                                                       int rows, float invB)
{
    __shared__ ushort Phi_u[2][32][LSTRIDE];   // 9KB
    __shared__ ushort Plo_u[2][32][LSTRIDE];   // 9KB
    __shared__ float  C_lds[NBINS];            // 4KB (reused as red[][] in phase 2)

    const int tid  = threadIdx.x;
    const int wav  = tid >> 6;
    const int lane = tid & 63;

    if (blockIdx.x == 0 && tid == 0) out[0] = 0.0f;   // ordered by grid.sync()

    // ================= phase 1: hist (R12-verified body) =================
    const int r0 = blockIdx.x * 256 + tid;     // batch 0 row
    const int r1 = r0 + 128;                   // batch 1 row

    float v0[10], v1[10];
    float valid0 = 1.0f, valid1 = 1.0f;
    if (r0 < rows) {
        const float2* a2 = (const float2*)(act + (size_t)r0 * 10);
        #pragma unroll
        for (int k = 0; k < 5; ++k) { float2 t = a2[k]; v0[2*k] = t.x; v0[2*k+1] = t.y; }
    } else {
        valid0 = 0.0f;
        #pragma unroll
        for (int k = 0; k < 10; ++k) v0[k] = 0.0f;
    }
    if (r1 < rows) {
        const float2* a2 = (const float2*)(act + (size_t)r1 * 10);
        #pragma unroll
        for (int k = 0; k < 5; ++k) { float2 t = a2[k]; v1[2*k] = t.x; v1[2*k+1] = t.y; }
    } else {
        valid1 = 0.0f;
        #pragma unroll
        for (int k = 0; k < 10; ++k) v1[k] = 0.0f;
    }

    const int m  = lane & 31;
    const int kh = (lane >> 5) * 8;      // 0 or 8
    f32x16 acc = {};

    // ---- batch 0 ----
    {
        float hi[32], lo[32];
        make_trees(v0, valid0, hi, lo);
        #pragma unroll
        for (int q = 0; q < 32; ++q) {
            __hip_bfloat16 bh = __float2bfloat16(hi[q]);
            __hip_bfloat16 bl = __float2bfloat16(lo[q]);
            Phi_u[wav][q][lane] = *(const ushort*)&bh;
            Plo_u[wav][q][lane] = *(const ushort*)&bl;
        }
        __syncthreads();
        #pragma unroll
        for (int t = 0; t < 4; ++t) {
            const short8 a = *(const short8*)&Phi_u[wav][m][kh + 16 * t];
            const short8 b = *(const short8*)&Plo_u[wav][m][kh + 16 * t];
            acc = __builtin_amdgcn_mfma_f32_32x32x16_bf16(a, b, acc, 0, 0, 0);
        }
        __syncthreads();
    }
    // ---- batch 1 ----
    {
        float hi[32], lo[32];
        make_trees(v1, valid1, hi, lo);
        #pragma unroll
        for (int q = 0; q < 32; ++q) {
            __hip_bfloat16 bh = __float2bfloat16(hi[q]);
            __hip_bfloat16 bl = __float2bfloat16(lo[q]);
            Phi_u[wav][q][lane] = *(const ushort*)&bh;
            Plo_u[wav][q][lane] = *(const ushort*)&bl;
        }
        __syncthreads();
        #pragma unroll
        for (int t = 0; t < 4; ++t) {
            const short8 a = *(const short8*)&Phi_u[wav][m][kh + 16 * t];
            const short8 b = *(const short8*)&Plo_u[wav][m][kh + 16 * t];
            acc = __builtin_amdgcn_mfma_f32_32x32x16_bf16(a, b, acc, 0, 0, 0);
        }
    }

    // Merge 2 waves without atomics: wave1 stores, wave0 adds. 2/bank = free.
    if (wav == 1) {
        #pragma unroll
        for (int r = 0; r < 16; ++r)
            C_lds[r * 64 + lane] = acc[r];
    }
    __syncthreads();
    if (wav == 0) {
        #pragma unroll
        for (int r = 0; r < 16; ++r)
            C_lds[r * 64 + lane] += acc[r];
    }
    __syncthreads();

    {
        float4* dst4 = (float4*)(gC + (size_t)blockIdx.x * NBINS);
        const float4* src4 = (const float4*)C_lds;
        dst4[tid]       = src4[tid];
        dst4[tid + 128] = src4[tid + 128];
    }

    // ================= grid-wide sync =================
    cg::this_grid().sync();

    // ================= phase 2: reduce + finalize =================
    // Blocks 0..255 each own 4 bins. Thread (g=tid>>2 in 0..31, b=tid&3) sums
    // partials g+32j (j=0..15) with 4 independent accumulators (anti-R9 MLP).
    if (blockIdx.x < 256) {
        float (*red)[4] = (float (*)[4])C_lds;   // reuse LDS: [32][4]
        const int g   = tid >> 2;                // 0..31
        const int b   = tid & 3;                 // 0..3
        const int bin = blockIdx.x * 4 + b;

        const float* p = gC + (size_t)g * NBINS + bin;
        float a0 = 0.f, a1 = 0.f, a2 = 0.f, a3 = 0.f;
        #pragma unroll
        for (int j = 0; j < 16; j += 4) {
            a0 += p[(size_t)(j + 0) * 32 * NBINS];
            a1 += p[(size_t)(j + 1) * 32 * NBINS];
            a2 += p[(size_t)(j + 2) * 32 * NBINS];
            a3 += p[(size_t)(j + 3) * 32 * NBINS];
        }
        __syncthreads();                         // C_lds no longer read as phase-1 data
        red[g][b] = (a0 + a1) + (a2 + a3);
        __syncthreads();

        if (tid < 4) {
            float t = 0.0f;
            #pragma unroll
            for (int k = 0; k < 32; ++k) t += red[k][tid];
            const float pa = t * invB;
            float e = pa * log2f(fmaxf(pa, 1e-12f));   // sum p*log2(clip(p))
            e += __shfl_down(e, 2);
            e += __shfl_down(e, 1);
            if (tid == 0) atomicAdd(out, e);           // 256 adds total
        }
    }
}

extern "C" void kernel_launch(void* const* d_in, const int* in_sizes, int n_in,
                              void* d_out, int out_size, void* d_ws, size_t ws_size,
                              hipStream_t stream)
{
    const float* act = (const float*)d_in[0];
    int rows = in_sizes[0] / 10;              // B = 131072 = 512 * 256
    float* gC  = (float*)d_ws;                // NPART x NBINS partials (2MB)
    float* out = (float*)d_out;
    float invB = 1.0f / (float)rows;

    void* args[] = { (void*)&act, (void*)&gC, (void*)&out, (void*)&rows, (void*)&invB };
    hipLaunchCooperativeKernel((void*)fused_kernel, dim3(NPART), dim3(128),
                               args, 0, stream);
}

// Round 14
// 14.067 us; speedup vs baseline: 4.9435x; 4.9435x over previous
//
#include <hip/hip_runtime.h>
#include <hip/hip_bf16.h>
#include <math.h>

#define NBINS   1024
#define NPART   512     // hist grid: 512 blocks x (2 waves x 128 k-rows)
#define LSTRIDE 136     // ushorts per bin-row: 272B, 16B-aligned; cols 128..135 pad

typedef __attribute__((ext_vector_type(8)))  short short8;   // 8 bf16 = 4 VGPR
typedef __attribute__((ext_vector_type(16))) float f32x16;   // MFMA 32x32 acc

// R12 shell (14.4us verified), hist staging reworked: the two 128-row batches
// are interleaved in LDS as ushort2{batch0,batch1} -> 64 ds_write_b32/thread
// (was 128 ds_write_b16), 2 barriers (was 4), K=128 via 8 MFMAs reading the
// interleaved panel directly (k' = 2*slot+batch is a bijection over 128 rows;
// sum over k is order-invariant). Reduce kernel byte-identical to R12.

__device__ __forceinline__ void make_trees(const float v[10], float valid,
                                           float hi[32], float lo[32])
{
    {
        float t2[2], t4[4], t8[8], t16[16];
        t2[0] = valid * (1.0f - v[0]); t2[1] = valid * v[0];
        #pragma unroll
        for (int k = 0; k < 4; ++k)  t4[k]  = t2[k >> 1]  * ((k & 1) ? v[1] : 1.0f - v[1]);
        #pragma unroll
        for (int k = 0; k < 8; ++k)  t8[k]  = t4[k >> 1]  * ((k & 1) ? v[2] : 1.0f - v[2]);
        #pragma unroll
        for (int k = 0; k < 16; ++k) t16[k] = t8[k >> 1]  * ((k & 1) ? v[3] : 1.0f - v[3]);
        #pragma unroll
        for (int k = 0; k < 32; ++k) hi[k]  = t16[k >> 1] * ((k & 1) ? v[4] : 1.0f - v[4]);
    }
    {
        float t2[2], t4[4], t8[8], t16[16];
        t2[0] = 1.0f - v[5]; t2[1] = v[5];
        #pragma unroll
        for (int k = 0; k < 4; ++k)  t4[k]  = t2[k >> 1]  * ((k & 1) ? v[6] : 1.0f - v[6]);
        #pragma unroll
        for (int k = 0; k < 8; ++k)  t8[k]  = t4[k >> 1]  * ((k & 1) ? v[7] : 1.0f - v[7]);
        #pragma unroll
        for (int k = 0; k < 16; ++k) t16[k] = t8[k >> 1]  * ((k & 1) ? v[8] : 1.0f - v[8]);
        #pragma unroll
        for (int k = 0; k < 32; ++k) lo[k]  = t16[k >> 1] * ((k & 1) ? v[9] : 1.0f - v[9]);
    }
}

__device__ __forceinline__ uint pack2(float a, float b)
{
    __hip_bfloat16 ba = __float2bfloat16(a);
    __hip_bfloat16 bb = __float2bfloat16(b);
    return (uint)(*(const ushort*)&ba) | ((uint)(*(const ushort*)&bb) << 16);
}

__global__ __launch_bounds__(128, 2) void hist_kernel(const float* __restrict__ act,
                                                      float* __restrict__ gC,
                                                      float* __restrict__ out,
                                                      int rows)
{
    __shared__ ushort Phi_u[2][32][LSTRIDE];   // 17KB
    __shared__ ushort Plo_u[2][32][LSTRIDE];   // 17KB
    __shared__ float  C_lds[NBINS];            // 4KB  (38KB total -> 2 blocks/CU)

    const int tid  = threadIdx.x;
    const int wav  = tid >> 6;
    const int lane = tid & 63;

    // re-init out each call; kernel boundary orders this before reduce's atomics
    if (blockIdx.x == 0 && tid == 0) out[0] = 0.0f;

    const int r0 = blockIdx.x * 256 + tid;     // batch 0 row
    const int r1 = r0 + 128;                   // batch 1 row

    float v0[10], v1[10];
    float valid0 = 1.0f, valid1 = 1.0f;
    if (r0 < rows) {
        const float2* a2 = (const float2*)(act + (size_t)r0 * 10);
        #pragma unroll
        for (int k = 0; k < 5; ++k) { float2 t = a2[k]; v0[2*k] = t.x; v0[2*k+1] = t.y; }
    } else {
        valid0 = 0.0f;
        #pragma unroll
        for (int k = 0; k < 10; ++k) v0[k] = 0.0f;
    }
    if (r1 < rows) {
        const float2* a2 = (const float2*)(act + (size_t)r1 * 10);
        #pragma unroll
        for (int k = 0; k < 5; ++k) { float2 t = a2[k]; v1[2*k] = t.x; v1[2*k+1] = t.y; }
    } else {
        valid1 = 0.0f;
        #pragma unroll
        for (int k = 0; k < 10; ++k) v1[k] = 0.0f;
    }

    // Both trees (f32), then pack batch-pairs and stage once.
    float hi0[32], lo0[32], hi1[32], lo1[32];
    make_trees(v0, valid0, hi0, lo0);
    make_trees(v1, valid1, hi1, lo1);

    // Write ushort2{b0,b1} at [q][2*lane]: dword banks (68q+lane)%32 -> 2/bank free.
    {
        #pragma unroll
        for (int q = 0; q < 32; ++q) {
            *(uint*)&Phi_u[wav][q][2 * lane] = pack2(hi0[q], hi1[q]);
            *(uint*)&Plo_u[wav][q][2 * lane] = pack2(lo0[q], lo1[q]);
        }
    }

    __syncthreads();

    // Phase 2: C(32x32) += Phi^T * Plo over K=128 interleaved rows, 8 MFMAs.
    // Fragment k' = 16t + 8h + i; panel col k' holds row (k'>>1) + 128*(k'&1).
    const int m = lane & 31;
    const int h = lane >> 5;             // 0 or 1

    f32x16 acc = {};
    #pragma unroll
    for (int t = 0; t < 8; ++t) {
        const short8 a = *(const short8*)&Phi_u[wav][m][16 * t + 8 * h];  // 16B aligned
        const short8 b = *(const short8*)&Plo_u[wav][m][16 * t + 8 * h];
        acc = __builtin_amdgcn_mfma_f32_32x32x16_bf16(a, b, acc, 0, 0, 0);
    }

    // Merge 2 waves without atomics: wave1 stores, wave0 adds. 2/bank = free.
    if (wav == 1) {
        #pragma unroll
        for (int r = 0; r < 16; ++r)
            C_lds[r * 64 + lane] = acc[r];
    }
    __syncthreads();
    if (wav == 0) {
        #pragma unroll
        for (int r = 0; r < 16; ++r)
            C_lds[r * 64 + lane] += acc[r];
    }
    __syncthreads();

    // coalesced plain-store of the block's 4KB partial
    float4* dst4 = (float4*)(gC + (size_t)blockIdx.x * NBINS);
    const float4* src4 = (const float4*)C_lds;
    dst4[tid]       = src4[tid];
    dst4[tid + 128] = src4[tid + 128];
}

// Fused reduce + finalize, bins-complete-per-block (R12-verified). 128 blocks;
// block bx owns bins bx*8..bx*8+7; 4 independent accumulators per thread.
__global__ __launch_bounds__(256) void reduce_kernel(const float* __restrict__ gC,
                                                     float* __restrict__ out,
                                                     float invB)
{
    __shared__ float red[32][8];     // [partial-group][bin-local]
    const int tid = threadIdx.x;
    const int g   = tid >> 3;        // 0..31
    const int b   = tid & 7;         // 0..7
    const int bin = blockIdx.x * 8 + b;

    const float* p = gC + (size_t)g * NBINS + bin;   // +32*NBINS per step
    float a0 = 0.f, a1 = 0.f, a2 = 0.f, a3 = 0.f;
    #pragma unroll
    for (int j = 0; j < 16; j += 4) {
        a0 += p[(size_t)(j + 0) * 32 * NBINS];
        a1 += p[(size_t)(j + 1) * 32 * NBINS];
        a2 += p[(size_t)(j + 2) * 32 * NBINS];
        a3 += p[(size_t)(j + 3) * 32 * NBINS];
    }
    red[g][b] = (a0 + a1) + (a2 + a3);
    __syncthreads();

    if (tid < 8) {
        float t = 0.0f;
        #pragma unroll
        for (int k = 0; k < 32; ++k) t += red[k][tid];
        const float pa = t * invB;
        float e = pa * log2f(fmaxf(pa, 1e-12f));   // sum p*log2(clip(p)) = -joint_h
        e += __shfl_down(e, 4);
        e += __shfl_down(e, 2);
        e += __shfl_down(e, 1);
        if (tid == 0) atomicAdd(out, e);           // 128 adds total, device scope
    }
}

extern "C" void kernel_launch(void* const* d_in, const int* in_sizes, int n_in,
                              void* d_out, int out_size, void* d_ws, size_t ws_size,
                              hipStream_t stream)
{
    const float* act = (const float*)d_in[0];
    const int rows = in_sizes[0] / 10;        // B = 131072 = 512 * 256
    float* gC  = (float*)d_ws;                // NPART x NBINS partials (2MB)
    float* out = (float*)d_out;

    hist_kernel<<<NPART, 128, 0, stream>>>(act, gC, out, rows);
    reduce_kernel<<<128, 256, 0, stream>>>(gC, out, 1.0f / (float)rows);
}

// Round 15
// 13.737 us; speedup vs baseline: 5.0624x; 1.0240x over previous
//
#include <hip/hip_runtime.h>
#include <hip/hip_bf16.h>
#include <math.h>

#define NBINS   1024
#define NPART   256     // hist grid: 256 blocks x 256 threads (4 waves x 128 k-rows)
#define PPC     8       // partials per reduce-thread (NPART/32)
#define LSTRIDE 136     // ushorts per bin-row: 272B, 16B-aligned; cols 128..135 pad

typedef __attribute__((ext_vector_type(8)))  short short8;   // 8 bf16 = 4 VGPR
typedef __attribute__((ext_vector_type(16))) float f32x16;   // MFMA 32x32 acc

// R14 structure re-packed into fatter blocks: 256 blocks x 4 waves (1/CU, one
// dispatch round; was 512 skinny blocks = 2 rounds). Per-thread work identical
// to R14. Partials 2MB -> 1MB. Wave merge = 2-stage LDS tree; wave0 stores
// merged C directly from registers (no C_lds round-trip).

__device__ __forceinline__ void make_trees(const float v[10], float valid,
                                           float hi[32], float lo[32])
{
    {
        float t2[2], t4[4], t8[8], t16[16];
        t2[0] = valid * (1.0f - v[0]); t2[1] = valid * v[0];
        #pragma unroll
        for (int k = 0; k < 4; ++k)  t4[k]  = t2[k >> 1]  * ((k & 1) ? v[1] : 1.0f - v[1]);
        #pragma unroll
        for (int k = 0; k < 8; ++k)  t8[k]  = t4[k >> 1]  * ((k & 1) ? v[2] : 1.0f - v[2]);
        #pragma unroll
        for (int k = 0; k < 16; ++k) t16[k] = t8[k >> 1]  * ((k & 1) ? v[3] : 1.0f - v[3]);
        #pragma unroll
        for (int k = 0; k < 32; ++k) hi[k]  = t16[k >> 1] * ((k & 1) ? v[4] : 1.0f - v[4]);
    }
    {
        float t2[2], t4[4], t8[8], t16[16];
        t2[0] = 1.0f - v[5]; t2[1] = v[5];
        #pragma unroll
        for (int k = 0; k < 4; ++k)  t4[k]  = t2[k >> 1]  * ((k & 1) ? v[6] : 1.0f - v[6]);
        #pragma unroll
        for (int k = 0; k < 8; ++k)  t8[k]  = t4[k >> 1]  * ((k & 1) ? v[7] : 1.0f - v[7]);
        #pragma unroll
        for (int k = 0; k < 16; ++k) t16[k] = t8[k >> 1]  * ((k & 1) ? v[8] : 1.0f - v[8]);
        #pragma unroll
        for (int k = 0; k < 32; ++k) lo[k]  = t16[k >> 1] * ((k & 1) ? v[9] : 1.0f - v[9]);
    }
}

__device__ __forceinline__ uint pack2(float a, float b)
{
    __hip_bfloat16 ba = __float2bfloat16(a);
    __hip_bfloat16 bb = __float2bfloat16(b);
    return (uint)(*(const ushort*)&ba) | ((uint)(*(const ushort*)&bb) << 16);
}

__global__ __launch_bounds__(256, 2) void hist_kernel(const float* __restrict__ act,
                                                      float* __restrict__ gC,
                                                      float* __restrict__ out,
                                                      int rows)
{
    __shared__ ushort Phi_u[4][32][LSTRIDE];   // 34KB
    __shared__ ushort Plo_u[4][32][LSTRIDE];   // 34KB
    __shared__ float  C_buf[2][NBINS];         // 8KB merge buffer (76KB total)

    const int tid  = threadIdx.x;
    const int wav  = tid >> 6;       // 0..3
    const int lane = tid & 63;

    // re-init out each call; kernel boundary orders this before reduce's atomics
    if (blockIdx.x == 0 && tid == 0) out[0] = 0.0f;

    const int r0 = blockIdx.x * 512 + tid;     // batch 0 row
    const int r1 = r0 + 256;                   // batch 1 row

    float v0[10], v1[10];
    float valid0 = 1.0f, valid1 = 1.0f;
    if (r0 < rows) {
        const float2* a2 = (const float2*)(act + (size_t)r0 * 10);
        #pragma unroll
        for (int k = 0; k < 5; ++k) { float2 t = a2[k]; v0[2*k] = t.x; v0[2*k+1] = t.y; }
    } else {
        valid0 = 0.0f;
        #pragma unroll
        for (int k = 0; k < 10; ++k) v0[k] = 0.0f;
    }
    if (r1 < rows) {
        const float2* a2 = (const float2*)(act + (size_t)r1 * 10);
        #pragma unroll
        for (int k = 0; k < 5; ++k) { float2 t = a2[k]; v1[2*k] = t.x; v1[2*k+1] = t.y; }
    } else {
        valid1 = 0.0f;
        #pragma unroll
        for (int k = 0; k < 10; ++k) v1[k] = 0.0f;
    }

    // Both trees (f32), then pack batch-pairs and stage once.
    float hi0[32], lo0[32], hi1[32], lo1[32];
    make_trees(v0, valid0, hi0, lo0);
    make_trees(v1, valid1, hi1, lo1);

    // ushort2{b0,b1} at [q][2*lane]: dword banks (68q+lane)%32 -> 2/bank = free.
    #pragma unroll
    for (int q = 0; q < 32; ++q) {
        *(uint*)&Phi_u[wav][q][2 * lane] = pack2(hi0[q], hi1[q]);
        *(uint*)&Plo_u[wav][q][2 * lane] = pack2(lo0[q], lo1[q]);
    }

    __syncthreads();

    // C(32x32) += Phi^T * Plo over K=128 interleaved rows, 8 MFMAs.
    const int m = lane & 31;
    const int h = lane >> 5;             // 0 or 1

    f32x16 acc = {};
    #pragma unroll
    for (int t = 0; t < 8; ++t) {
        const short8 a = *(const short8*)&Phi_u[wav][m][16 * t + 8 * h];  // 16B aligned
        const short8 b = *(const short8*)&Plo_u[wav][m][16 * t + 8 * h];
        acc = __builtin_amdgcn_mfma_f32_32x32x16_bf16(a, b, acc, 0, 0, 0);
    }

    // 2-stage merge tree (no atomics): {1->0, 3->2} then {2->0}; wave0 stores
    // directly from registers. Banks = lane%32 -> 2/bank = free.
    if (wav == 1 || wav == 3) {
        #pragma unroll
        for (int r = 0; r < 16; ++r)
            C_buf[wav >> 1][r * 64 + lane] = acc[r];
    }
    __syncthreads();
    if (wav == 0 || wav == 2) {
        #pragma unroll
        for (int r = 0; r < 16; ++r)
            acc[r] += C_buf[wav >> 1][r * 64 + lane];
    }
    __syncthreads();
    if (wav == 2) {
        #pragma unroll
        for (int r = 0; r < 16; ++r)
            C_buf[0][r * 64 + lane] = acc[r];
    }
    __syncthreads();
    if (wav == 0) {
        float* dst = gC + (size_t)blockIdx.x * NBINS;
        #pragma unroll
        for (int r = 0; r < 16; ++r)
            dst[r * 64 + lane] = acc[r] + C_buf[0][r * 64 + lane];  // 256B coalesced
    }
}

// Fused reduce + finalize, bins-complete-per-block (R12-verified geometry).
// 128 blocks x 256 threads; block owns 8 bins; thread (g,b) sums partials
// g+32j (j=0..7) with 4 independent accumulators.
__global__ __launch_bounds__(256) void reduce_kernel(const float* __restrict__ gC,
                                                     float* __restrict__ out,
                                                     float invB)
{
    __shared__ float red[32][8];     // [partial-group][bin-local]
    const int tid = threadIdx.x;
    const int g   = tid >> 3;        // 0..31
    const int b   = tid & 7;         // 0..7
    const int bin = blockIdx.x * 8 + b;

    const float* p = gC + (size_t)g * NBINS + bin;   // +32*NBINS per step
    float a0 = 0.f, a1 = 0.f, a2 = 0.f, a3 = 0.f;
    #pragma unroll
    for (int j = 0; j < PPC; j += 4) {
        a0 += p[(size_t)(j + 0) * 32 * NBINS];
        a1 += p[(size_t)(j + 1) * 32 * NBINS];
        a2 += p[(size_t)(j + 2) * 32 * NBINS];
        a3 += p[(size_t)(j + 3) * 32 * NBINS];
    }
    red[g][b] = (a0 + a1) + (a2 + a3);
    __syncthreads();

    if (tid < 8) {
        float t = 0.0f;
        #pragma unroll
        for (int k = 0; k < 32; ++k) t += red[k][tid];
        const float pa = t * invB;
        float e = pa * log2f(fmaxf(pa, 1e-12f));   // sum p*log2(clip(p)) = -joint_h
        e += __shfl_down(e, 4);
        e += __shfl_down(e, 2);
        e += __shfl_down(e, 1);
        if (tid == 0) atomicAdd(out, e);           // 128 adds total, device scope
    }
}

extern "C" void kernel_launch(void* const* d_in, const int* in_sizes, int n_in,
                              void* d_out, int out_size, void* d_ws, size_t ws_size,
                              hipStream_t stream)
{
    const float* act = (const float*)d_in[0];
    const int rows = in_sizes[0] / 10;        // B = 131072 = 256 * 512
    float* gC  = (float*)d_ws;                // NPART x NBINS partials (1MB)
    float* out = (float*)d_out;

    hist_kernel<<<NPART, 256, 0, stream>>>(act, gC, out, rows);
    reduce_kernel<<<128, 256, 0, stream>>>(gC, out, 1.0f / (float)rows);
}